// Round 15
// baseline (90976.056 us; speedup 1.0000x reference)
//
#include <hip/hip_runtime.h>
#include <hip/hip_bf16.h>
#include <stdint.h>

constexpr int kSEQ = 8192;
constexpr int kIN  = 1024;
constexpr int kH   = 2048;
constexpr int kG4  = 4 * kH;   // 8192 gate rows
constexpr int kNB  = 256;      // persistent workgroups (1 per CU)
constexpr int kHB  = kH / kNB; // 8 h-values owned per WG
constexpr int kWP  = kH + 16;  // LDS weight row stride

// ---- workspace layout (bytes) ----
constexpr size_t OFF_HBUF  = 0;          // u64 hbuf[2][kH]  (32 KB) tagged h words
constexpr size_t OFF_ABORT = 32768;      // uint32 abort flag
constexpr size_t OFF_HS    = 65536;      // bf16 hs[kSEQ][kH]   (32 MB)
constexpr size_t OFF_XP    = OFF_HS + (size_t)kSEQ * kH * 2; // bf16 xp[kSEQ][kG4] (128 MB)

__device__ __forceinline__ float bflo(uint32_t v) { return __uint_as_float(v << 16); }
__device__ __forceinline__ float bfhi(uint32_t v) { return __uint_as_float(v & 0xffff0000u); }

// ---------------------------------------------------------------------------
// Kernel 1: x_proj[m][n] = sum_k input[m][k] * W_ih[n][k] + b_ih[n] + b_hh[n]
// fp32 LDS-tiled GEMM, 64x64 tile, BK=16, 256 threads, 4x4 per thread.
// ---------------------------------------------------------------------------
__global__ __launch_bounds__(256) void k_xproj(const float* __restrict__ A,
                                               const float* __restrict__ B,
                                               const float* __restrict__ bih,
                                               const float* __restrict__ bhh,
                                               __hip_bfloat16* __restrict__ C)
{
    __shared__ float As[16][65];
    __shared__ float Bs[16][65];

    const int bx = blockIdx.x & 127;   // n tile
    const int by = blockIdx.x >> 7;    // m tile
    const int tid = threadIdx.x;
    const int r  = tid >> 2;           // 0..63 row within tile
    const int kq = (tid & 3) << 2;     // 0,4,8,12
    const int tx = tid & 15;
    const int ty = tid >> 4;
    const int m0 = by * 64, n0 = bx * 64;

    float acc[4][4] = {};

    for (int k0 = 0; k0 < kIN; k0 += 16) {
        float4 av = *(const float4*)&A[(size_t)(m0 + r) * kIN + k0 + kq];
        float4 bv = *(const float4*)&B[(size_t)(n0 + r) * kIN + k0 + kq];
        __syncthreads();   // protect previous iteration's reads
        As[kq + 0][r] = av.x; As[kq + 1][r] = av.y; As[kq + 2][r] = av.z; As[kq + 3][r] = av.w;
        Bs[kq + 0][r] = bv.x; Bs[kq + 1][r] = bv.y; Bs[kq + 2][r] = bv.z; Bs[kq + 3][r] = bv.w;
        __syncthreads();
        #pragma unroll
        for (int k = 0; k < 16; ++k) {
            float a0 = As[k][ty * 4 + 0], a1 = As[k][ty * 4 + 1];
            float a2 = As[k][ty * 4 + 2], a3 = As[k][ty * 4 + 3];
            float b0 = Bs[k][tx * 4 + 0], b1 = Bs[k][tx * 4 + 1];
            float b2 = Bs[k][tx * 4 + 2], b3 = Bs[k][tx * 4 + 3];
            acc[0][0] += a0 * b0; acc[0][1] += a0 * b1; acc[0][2] += a0 * b2; acc[0][3] += a0 * b3;
            acc[1][0] += a1 * b0; acc[1][1] += a1 * b1; acc[1][2] += a1 * b2; acc[1][3] += a1 * b3;
            acc[2][0] += a2 * b0; acc[2][1] += a2 * b1; acc[2][2] += a2 * b2; acc[2][3] += a2 * b3;
            acc[3][0] += a3 * b0; acc[3][1] += a3 * b1; acc[3][2] += a3 * b2; acc[3][3] += a3 * b3;
        }
    }

    #pragma unroll
    for (int i = 0; i < 4; ++i) {
        const int m = m0 + ty * 4 + i;
        #pragma unroll
        for (int j = 0; j < 4; ++j) {
            const int n = n0 + tx * 4 + j;
            C[(size_t)m * kG4 + n] = __float2bfloat16(acc[i][j] + bih[n] + bhh[n]);
        }
    }
}

// ---------------------------------------------------------------------------
// Kernel 2: persistent LSTM recurrence. 256 WGs x 256 threads, 1 WG/CU.
// R14 = R10 + CHUNK-PIPELINED CONSUMPTION, ZERO steady-state barriers.
//  - 1-hop data-carrying poll (kept): thread tid busy-polls its 8 u64 words
//    (tag == t), no backoff; the successful poll returns the data.
//  - After staging its 8 floats to hl2[t&1], the thread RELEASE-adds to LDS
//    counter cnts[t&1][tid/8]. Monotone target 8*((t>>1)+1) (no resets).
//  - The matvec consumes chunks 0..31 in order, ACQUIRE-spinning per chunk
//    only when its stager hasn't landed -> early chunks' compute overlaps
//    late producers' propagation.
//  - Skew proof (zero barriers): a wave reaches step t only after its poll
//    saw ALL 2048 words tagged t, i.e. every wave of every WG finished step
//    t-1 (incl. reading buffers of parity t&1). Hence writers at step t
//    never touch memory a lagging reader still needs; skew <= 1 step.
//  - Liveness: shared budget + sticky abort in both spins; wave-uniform exit.
// ---------------------------------------------------------------------------
__global__ __launch_bounds__(256, 1) void k_lstm(const float* __restrict__ Whh,
                                                 const __hip_bfloat16* __restrict__ xp,
                                                 unsigned long long* __restrict__ hbuf, // [2][kH]
                                                 uint32_t* __restrict__ abortf,
                                                 __hip_bfloat16* __restrict__ hs)
{
    extern __shared__ char smem[];
    __hip_bfloat16* Wl   = (__hip_bfloat16*)smem;                      // [32][kWP] bf16
    float*          hl2  = (float*)(smem + 32 * kWP * 2);              // [2][kH] fp32
    uint32_t*       cnts = (uint32_t*)(smem + 32 * kWP * 2 + 2 * kH * 4); // [2][32]

    const int wg  = blockIdx.x;
    const int tid = threadIdx.x;
    const int w   = tid >> 6;   // wave id
    const int l   = tid & 63;
    const int hb  = wg * kHB;

    if (tid < 64) cnts[tid] = 0;   // zero chunk counters (2*32)

    // ---- one-time: stage W_hh slice, per-wave gate-complete mapping ----
    // LDS row lr holds W_hh row (gate lr&3, h-local 2*(lr>>3) + ((lr>>2)&1))
    {
        const int lr = tid >> 3;
        const int g  = lr & 3;
        const int jl = 2 * (lr >> 3) + ((lr >> 2) & 1);
        const int cb = (tid & 7) * 256;
        const float* src = Whh + (size_t)(g * kH + hb + jl) * kH + cb;
        __hip_bfloat16* dst = Wl + (size_t)lr * kWP + cb;
        for (int c = 0; c < 256; c += 4) {
            float4 v = *(const float4*)(src + c);
            dst[c + 0] = __float2bfloat16(v.x);
            dst[c + 1] = __float2bfloat16(v.y);
            dst[c + 2] = __float2bfloat16(v.z);
            dst[c + 3] = __float2bfloat16(v.w);
        }
    }
    __syncthreads();   // weights + counters ready (only barrier in the kernel)

    const __hip_bfloat16* wrow = Wl + (size_t)(w * 8 + (l >> 3)) * kWP;
    const int kbase   = (l & 7) * 8;
    const int jg      = hb + 2 * w + (l >> 5); // this half-wave's h index
    const int mychunk = tid >> 3;              // chunk this thread stages
    float c_state = 0.0f;
    uint32_t budget = 0;

    for (int t = 0; t < kSEQ; ++t) {
        const int b = t & 1;
        const uint32_t tgt8 = 8u * ((uint32_t)(t >> 1) + 1u);

        // ---- issue this lane's 4 x_proj gate values early (retire under poll) ----
        const __hip_bfloat16* xr = xp + (size_t)t * kG4 + jg;
        const float xi = __bfloat162float(xr[0]);
        const float xf = __bfloat162float(xr[kH]);
        const float xg = __bfloat162float(xr[2 * kH]);
        const float xo = __bfloat162float(xr[3 * kH]);

        // ---- stage own chunk: 1-hop data-carrying poll (R10 structure) ----
        float* hw = hl2 + (size_t)b * kH + tid * 8;
        int dead = 0;
        if (t == 0) {
            #pragma unroll
            for (int j = 0; j < 8; ++j) hw[j] = 0.f;
        } else {
            const unsigned long long* src = hbuf + (size_t)((t - 1) & 1) * kH + tid * 8;
            const uint32_t tag = (uint32_t)t;
            unsigned long long v[8];
            for (;;) {
                #pragma unroll
                for (int j = 0; j < 8; ++j)
                    v[j] = __hip_atomic_load(src + j, __ATOMIC_RELAXED, __HIP_MEMORY_SCOPE_AGENT);
                bool ok = true;
                #pragma unroll
                for (int j = 0; j < 8; ++j) ok &= ((uint32_t)v[j] == tag);
                if (ok) break;
                if ((++budget & 15) == 0) {
                    if (__hip_atomic_load(abortf, __ATOMIC_RELAXED,
                                          __HIP_MEMORY_SCOPE_AGENT) != 0u) { dead = 1; break; }
                    if (budget > (1u << 21)) { dead = 1; break; }
                }
            }
            #pragma unroll
            for (int j = 0; j < 8; ++j) hw[j] = __uint_as_float((uint32_t)(v[j] >> 32));
        }
        if (__any(dead)) {   // wave-uniform bail; bounded, never hangs
            __hip_atomic_store(abortf, 1u, __ATOMIC_RELAXED, __HIP_MEMORY_SCOPE_AGENT);
            return;
        }
        __hip_atomic_fetch_add(&cnts[b * 32 + mychunk], 1u,
                               __ATOMIC_RELEASE, __HIP_MEMORY_SCOPE_WORKGROUP);

        // ---- matvec, chunk-gated in order: overlap compute with arrivals ----
        const float* hv = hl2 + (size_t)b * kH;
        float acc = 0.f;
        #pragma unroll 4
        for (int it = 0; it < 32; ++it) {
            if (__hip_atomic_load(&cnts[b * 32 + it], __ATOMIC_ACQUIRE,
                                  __HIP_MEMORY_SCOPE_WORKGROUP) < tgt8) {
                int cdead = 0;
                for (;;) {
                    if (__hip_atomic_load(&cnts[b * 32 + it], __ATOMIC_ACQUIRE,
                                          __HIP_MEMORY_SCOPE_WORKGROUP) >= tgt8) break;
                    if ((++budget & 255) == 0) {
                        if (__hip_atomic_load(abortf, __ATOMIC_RELAXED,
                                              __HIP_MEMORY_SCOPE_AGENT) != 0u ||
                            budget > (1u << 21)) { cdead = 1; break; }
                    }
                }
                if (__any(cdead)) {
                    __hip_atomic_store(abortf, 1u, __ATOMIC_RELAXED, __HIP_MEMORY_SCOPE_AGENT);
                    return;
                }
            }
            const int k = it * 64 + kbase;
            uint4 wv = *(const uint4*)(wrow + k);
            float4 h0 = *(const float4*)(hv + k);
            float4 h1 = *(const float4*)(hv + k + 4);
            acc += bflo(wv.x) * h0.x + bfhi(wv.x) * h0.y
                 + bflo(wv.y) * h0.z + bfhi(wv.y) * h0.w
                 + bflo(wv.z) * h1.x + bfhi(wv.z) * h1.y
                 + bflo(wv.w) * h1.z + bfhi(wv.w) * h1.w;
        }
        acc += __shfl_xor(acc, 1);
        acc += __shfl_xor(acc, 2);
        acc += __shfl_xor(acc, 4);   // every lane of each 8-group has its row sum

        // ---- collect 4 gates for this half-wave's h index; update; publish ----
        const int base = l & 32;
        const float gi = __shfl(acc, base + 0)  + xi;
        const float gf = __shfl(acc, base + 8)  + xf;
        const float gg = __shfl(acc, base + 16) + xg;
        const float go = __shfl(acc, base + 24) + xo;
        const float si = 1.f / (1.f + expf(-gi));
        const float sf = 1.f / (1.f + expf(-gf));
        const float tg = tanhf(gg);
        const float so = 1.f / (1.f + expf(-go));
        c_state = sf * c_state + si * tg;            // valid per half-wave
        const float hvv = so * tanhf(c_state);
        if ((l & 31) == 0) {
            hs[(size_t)t * kH + jg] = __float2bfloat16(hvv);
            const unsigned long long pv =
                ((unsigned long long)__float_as_uint(hvv) << 32) | (uint32_t)(t + 1);
            __hip_atomic_store(hbuf + (size_t)b * kH + jg, pv,
                               __ATOMIC_RELAXED, __HIP_MEMORY_SCOPE_AGENT);
        }
        // no barrier: global tag-poll bounds skew to <=1 step (see header proof)
    }
}

// ---------------------------------------------------------------------------
// Kernel 3: out[t] = sigmoid(hs[t] . W_lin + b_lin). One wave per t.
// ---------------------------------------------------------------------------
__global__ __launch_bounds__(256) void k_out(const __hip_bfloat16* __restrict__ hs,
                                             const float* __restrict__ wlin,
                                             const float* __restrict__ blin,
                                             float* __restrict__ out)
{
    const int w = threadIdx.x >> 6, l = threadIdx.x & 63;
    const int t = blockIdx.x * 4 + w;
    const __hip_bfloat16* row = hs + (size_t)t * kH;
    float acc = 0.f;
    #pragma unroll
    for (int i = 0; i < 4; ++i) {
        const int k = i * 512 + l * 8;
        uint4 hv = *(const uint4*)(row + k);
        float4 w0 = *(const float4*)(wlin + k);
        float4 w1 = *(const float4*)(wlin + k + 4);
        acc += bflo(hv.x) * w0.x + bfhi(hv.x) * w0.y
             + bflo(hv.y) * w0.z + bfhi(hv.y) * w0.w
             + bflo(hv.z) * w1.x + bfhi(hv.z) * w1.y
             + bflo(hv.w) * w1.z + bfhi(hv.w) * w1.w;
    }
    #pragma unroll
    for (int s = 32; s >= 1; s >>= 1) acc += __shfl_xor(acc, s);
    if (l == 0) out[t] = 1.f / (1.f + expf(-(acc + blin[0])));
}

// ---------------------------------------------------------------------------
extern "C" void kernel_launch(void* const* d_in, const int* in_sizes, int n_in,
                              void* d_out, int out_size, void* d_ws, size_t ws_size,
                              hipStream_t stream)
{
    const float* input_seq = (const float*)d_in[0];
    const float* W_ih      = (const float*)d_in[1];
    const float* W_hh      = (const float*)d_in[2];
    const float* b_ih      = (const float*)d_in[3];
    const float* b_hh      = (const float*)d_in[4];
    const float* W_lin     = (const float*)d_in[5];
    const float* b_lin     = (const float*)d_in[6];
    float* out = (float*)d_out;
    char*  ws  = (char*)d_ws;

    unsigned long long* hbuf = (unsigned long long*)(ws + OFF_HBUF);
    uint32_t*           abf  = (uint32_t*)(ws + OFF_ABORT);
    __hip_bfloat16*     hs   = (__hip_bfloat16*)(ws + OFF_HS);
    __hip_bfloat16*     xpb  = (__hip_bfloat16*)(ws + OFF_XP);

    // zero hbuf tags + abort each call (harness does not re-poison between replays)
    hipMemsetAsync(ws, 0, 65536, stream);

    k_xproj<<<dim3(128 * 128), dim3(256), 0, stream>>>(input_seq, W_ih, b_ih, b_hh, xpb);

    constexpr int kLds = 32 * kWP * 2 + 2 * kH * 4 + 2 * 32 * 4;   // 148736 B
    hipFuncSetAttribute((const void*)k_lstm, hipFuncAttributeMaxDynamicSharedMemorySize, kLds);

    // Preferred: cooperative launch -> driver guarantees all 256 WGs co-resident,
    // so the tag-poll is provably live. Fallback: plain launch (whole-kernel
    // bounded spin + sticky abort still prevents any hang).
    {
        const float* a0 = W_hh; const __hip_bfloat16* a1 = xpb;
        unsigned long long* a2 = hbuf; uint32_t* a3 = abf; __hip_bfloat16* a4 = hs;
        void* args[5] = { &a0, &a1, &a2, &a3, &a4 };
        hipError_t ce = hipLaunchCooperativeKernel((const void*)k_lstm, dim3(kNB), dim3(256),
                                                   args, (unsigned)kLds, stream);
        if (ce != hipSuccess) {
            k_lstm<<<dim3(kNB), dim3(256), kLds, stream>>>(W_hh, xpb, hbuf, abf, hs);
        }
    }

    k_out<<<dim3(kSEQ / 4), dim3(256), 0, stream>>>(hs, W_lin, b_lin, out);
}

// Round 16
// 53167.358 us; speedup vs baseline: 1.7111x; 1.7111x over previous
//
#include <hip/hip_runtime.h>
#include <hip/hip_bf16.h>
#include <stdint.h>

constexpr int kSEQ = 8192;
constexpr int kIN  = 1024;
constexpr int kH   = 2048;
constexpr int kG4  = 4 * kH;   // 8192 gate rows
constexpr int kNB  = 256;      // persistent workgroups (1 per CU)
constexpr int kHB  = kH / kNB; // 8 h-values owned per WG
constexpr int kWP  = kH + 16;  // LDS weight row stride

// ---- workspace layout (bytes) ----
constexpr size_t OFF_HBUF  = 0;          // u64 hbuf[2][kH]  (32 KB) tagged h words
constexpr size_t OFF_ABORT = 32768;      // uint32 abort flag
constexpr size_t OFF_HS    = 65536;      // bf16 hs[kSEQ][kH]   (32 MB)
constexpr size_t OFF_XP    = OFF_HS + (size_t)kSEQ * kH * 2; // bf16 xp[kSEQ][kG4] (128 MB)

typedef unsigned int uint4v __attribute__((ext_vector_type(4)));

__device__ __forceinline__ float bflo(uint32_t v) { return __uint_as_float(v << 16); }
__device__ __forceinline__ float bfhi(uint32_t v) { return __uint_as_float(v & 0xffff0000u); }

// ---------------------------------------------------------------------------
// Kernel 1: x_proj[m][n] = sum_k input[m][k] * W_ih[n][k] + b_ih[n] + b_hh[n]
// fp32 LDS-tiled GEMM, 64x64 tile, BK=16, 256 threads, 4x4 per thread.
// ---------------------------------------------------------------------------
__global__ __launch_bounds__(256) void k_xproj(const float* __restrict__ A,
                                               const float* __restrict__ B,
                                               const float* __restrict__ bih,
                                               const float* __restrict__ bhh,
                                               __hip_bfloat16* __restrict__ C)
{
    __shared__ float As[16][65];
    __shared__ float Bs[16][65];

    const int bx = blockIdx.x & 127;   // n tile
    const int by = blockIdx.x >> 7;    // m tile
    const int tid = threadIdx.x;
    const int r  = tid >> 2;           // 0..63 row within tile
    const int kq = (tid & 3) << 2;     // 0,4,8,12
    const int tx = tid & 15;
    const int ty = tid >> 4;
    const int m0 = by * 64, n0 = bx * 64;

    float acc[4][4] = {};

    for (int k0 = 0; k0 < kIN; k0 += 16) {
        float4 av = *(const float4*)&A[(size_t)(m0 + r) * kIN + k0 + kq];
        float4 bv = *(const float4*)&B[(size_t)(n0 + r) * kIN + k0 + kq];
        __syncthreads();   // protect previous iteration's reads
        As[kq + 0][r] = av.x; As[kq + 1][r] = av.y; As[kq + 2][r] = av.z; As[kq + 3][r] = av.w;
        Bs[kq + 0][r] = bv.x; Bs[kq + 1][r] = bv.y; Bs[kq + 2][r] = bv.z; Bs[kq + 3][r] = bv.w;
        __syncthreads();
        #pragma unroll
        for (int k = 0; k < 16; ++k) {
            float a0 = As[k][ty * 4 + 0], a1 = As[k][ty * 4 + 1];
            float a2 = As[k][ty * 4 + 2], a3 = As[k][ty * 4 + 3];
            float b0 = Bs[k][tx * 4 + 0], b1 = Bs[k][tx * 4 + 1];
            float b2 = Bs[k][tx * 4 + 2], b3 = Bs[k][tx * 4 + 3];
            acc[0][0] += a0 * b0; acc[0][1] += a0 * b1; acc[0][2] += a0 * b2; acc[0][3] += a0 * b3;
            acc[1][0] += a1 * b0; acc[1][1] += a1 * b1; acc[1][2] += a1 * b2; acc[1][3] += a1 * b3;
            acc[2][0] += a2 * b0; acc[2][1] += a2 * b1; acc[2][2] += a2 * b2; acc[2][3] += a2 * b3;
            acc[3][0] += a3 * b0; acc[3][1] += a3 * b1; acc[3][2] += a3 * b2; acc[3][3] += a3 * b3;
        }
    }

    #pragma unroll
    for (int i = 0; i < 4; ++i) {
        const int m = m0 + ty * 4 + i;
        #pragma unroll
        for (int j = 0; j < 4; ++j) {
            const int n = n0 + tx * 4 + j;
            C[(size_t)m * kG4 + n] = __float2bfloat16(acc[i][j] + bih[n] + bhh[n]);
        }
    }
}

// ---------------------------------------------------------------------------
// Kernel 2: persistent LSTM recurrence. 256 WGs x 256 threads, 1 WG/CU.
// R16 = R10 frame (proven best family) with the poll sweep done as
// 4x global_load_dwordx4 sc0 sc1 (device-coherent, 16B each) + one vmcnt(0)
// in a single asm block: 2x fewer coherent L3 ops per sweep than 8x atomic
// u64 loads, one wait instead of eight. Tag(u64 low dword) + data(high
// dword) sit in one aligned u64 inside a single 16B load from one 64B line
// -> per-word consistency preserved; tags still validate every word.
// Everything else identical to R10: single barrier/step, per-wave gate
// collection via shfl, relaxed tagged publish, no trailing barrier (tag
// poll bounds skew to <=1 step), bounded budget + sticky abort, coop launch.
// ---------------------------------------------------------------------------
__global__ __launch_bounds__(256, 1) void k_lstm(const float* __restrict__ Whh,
                                                 const __hip_bfloat16* __restrict__ xp,
                                                 unsigned long long* __restrict__ hbuf, // [2][kH]
                                                 uint32_t* __restrict__ abortf,
                                                 __hip_bfloat16* __restrict__ hs)
{
    extern __shared__ char smem[];
    __hip_bfloat16* Wl  = (__hip_bfloat16*)smem;              // [32][kWP] bf16
    float*          hl2 = (float*)(smem + 32 * kWP * 2);      // [2][kH] fp32

    const int wg  = blockIdx.x;
    const int tid = threadIdx.x;
    const int w   = tid >> 6;   // wave id
    const int l   = tid & 63;
    const int hb  = wg * kHB;

    // ---- one-time: stage W_hh slice, per-wave gate-complete mapping ----
    // LDS row lr holds W_hh row (gate lr&3, h-local 2*(lr>>3) + ((lr>>2)&1))
    {
        const int lr = tid >> 3;
        const int g  = lr & 3;
        const int jl = 2 * (lr >> 3) + ((lr >> 2) & 1);
        const int cb = (tid & 7) * 256;
        const float* src = Whh + (size_t)(g * kH + hb + jl) * kH + cb;
        __hip_bfloat16* dst = Wl + (size_t)lr * kWP + cb;
        for (int c = 0; c < 256; c += 4) {
            float4 v = *(const float4*)(src + c);
            dst[c + 0] = __float2bfloat16(v.x);
            dst[c + 1] = __float2bfloat16(v.y);
            dst[c + 2] = __float2bfloat16(v.z);
            dst[c + 3] = __float2bfloat16(v.w);
        }
    }
    __syncthreads();

    const __hip_bfloat16* wrow = Wl + (size_t)(w * 8 + (l >> 3)) * kWP;
    const int kbase = (l & 7) * 8;
    const int jg = hb + 2 * w + (l >> 5);     // this half-wave's h index (global)
    float c_state = 0.0f;
    uint32_t budget = 0;                      // whole-kernel retry budget

    for (int t = 0; t < kSEQ; ++t) {
        // ---- issue this lane's 4 x_proj gate values early (retire under poll) ----
        const __hip_bfloat16* xr = xp + (size_t)t * kG4 + jg;
        const float xi = __bfloat162float(xr[0]);
        const float xf = __bfloat162float(xr[kH]);
        const float xg = __bfloat162float(xr[2 * kH]);
        const float xo = __bfloat162float(xr[3 * kH]);

        // ---- gather h_{t-1} into hl2[t&1]: 64B/thread coherent sweep ----
        float* hw = hl2 + (size_t)(t & 1) * kH + tid * 8;
        int dead = 0;
        if (t == 0) {
            #pragma unroll
            for (int j = 0; j < 8; ++j) hw[j] = 0.f;
        } else {
            const unsigned long long* src = hbuf + (size_t)((t - 1) & 1) * kH + tid * 8;
            const uint32_t tag = (uint32_t)t;
            uint4v q0, q1, q2, q3;
            for (;;) {
                asm volatile(
                    "global_load_dwordx4 %0, %4, off sc0 sc1\n\t"
                    "global_load_dwordx4 %1, %4, off offset:16 sc0 sc1\n\t"
                    "global_load_dwordx4 %2, %4, off offset:32 sc0 sc1\n\t"
                    "global_load_dwordx4 %3, %4, off offset:48 sc0 sc1\n\t"
                    "s_waitcnt vmcnt(0)"
                    : "=&v"(q0), "=&v"(q1), "=&v"(q2), "=&v"(q3)
                    : "v"(src)
                    : "memory");
                bool ok = (q0[0] == tag) & (q0[2] == tag) & (q1[0] == tag) & (q1[2] == tag)
                        & (q2[0] == tag) & (q2[2] == tag) & (q3[0] == tag) & (q3[2] == tag);
                if (ok) break;
                if ((++budget & 15) == 0) {
                    if (__hip_atomic_load(abortf, __ATOMIC_RELAXED,
                                          __HIP_MEMORY_SCOPE_AGENT) != 0u) { dead = 1; break; }
                    if (budget > (1u << 21)) { dead = 1; break; }
                }
            }
            hw[0] = __uint_as_float(q0[1]); hw[1] = __uint_as_float(q0[3]);
            hw[2] = __uint_as_float(q1[1]); hw[3] = __uint_as_float(q1[3]);
            hw[4] = __uint_as_float(q2[1]); hw[5] = __uint_as_float(q2[3]);
            hw[6] = __uint_as_float(q3[1]); hw[7] = __uint_as_float(q3[3]);
        }
        if (__syncthreads_or(dead)) {   // single barrier/step; uniform exit
            __hip_atomic_store(abortf, 1u, __ATOMIC_RELAXED, __HIP_MEMORY_SCOPE_AGENT);
            return;
        }

        // ---- matvec: lane group r=l>>3 -> LDS row w*8+r; 32 iters x 8 MACs ----
        const float* hv = hl2 + (size_t)(t & 1) * kH;
        float acc = 0.f;
        #pragma unroll 8
        for (int it = 0; it < 32; ++it) {
            const int k = it * 64 + kbase;
            uint4 wv = *(const uint4*)(wrow + k);
            float4 h0 = *(const float4*)(hv + k);
            float4 h1 = *(const float4*)(hv + k + 4);
            acc += bflo(wv.x) * h0.x + bfhi(wv.x) * h0.y
                 + bflo(wv.y) * h0.z + bfhi(wv.y) * h0.w
                 + bflo(wv.z) * h1.x + bfhi(wv.z) * h1.y
                 + bflo(wv.w) * h1.z + bfhi(wv.w) * h1.w;
        }
        acc += __shfl_xor(acc, 1);
        acc += __shfl_xor(acc, 2);
        acc += __shfl_xor(acc, 4);   // every lane of each 8-group has its row sum

        // ---- collect 4 gates for this half-wave's h index; update; publish ----
        const int base = l & 32;
        const float gi = __shfl(acc, base + 0)  + xi;
        const float gf = __shfl(acc, base + 8)  + xf;
        const float gg = __shfl(acc, base + 16) + xg;
        const float go = __shfl(acc, base + 24) + xo;
        const float si = 1.f / (1.f + expf(-gi));
        const float sf = 1.f / (1.f + expf(-gf));
        const float tg = tanhf(gg);
        const float so = 1.f / (1.f + expf(-go));
        c_state = sf * c_state + si * tg;            // valid per half-wave
        const float hvv = so * tanhf(c_state);
        if ((l & 31) == 0) {
            hs[(size_t)t * kH + jg] = __float2bfloat16(hvv);
            const unsigned long long pv =
                ((unsigned long long)__float_as_uint(hvv) << 32) | (uint32_t)(t + 1);
            __hip_atomic_store(hbuf + (size_t)(t & 1) * kH + jg, pv,
                               __ATOMIC_RELAXED, __HIP_MEMORY_SCOPE_AGENT);
        }
        // no trailing barrier: tags + next step's single barrier self-synchronize
    }
}

// ---------------------------------------------------------------------------
// Kernel 3: out[t] = sigmoid(hs[t] . W_lin + b_lin). One wave per t.
// ---------------------------------------------------------------------------
__global__ __launch_bounds__(256) void k_out(const __hip_bfloat16* __restrict__ hs,
                                             const float* __restrict__ wlin,
                                             const float* __restrict__ blin,
                                             float* __restrict__ out)
{
    const int w = threadIdx.x >> 6, l = threadIdx.x & 63;
    const int t = blockIdx.x * 4 + w;
    const __hip_bfloat16* row = hs + (size_t)t * kH;
    float acc = 0.f;
    #pragma unroll
    for (int i = 0; i < 4; ++i) {
        const int k = i * 512 + l * 8;
        uint4 hv = *(const uint4*)(row + k);
        float4 w0 = *(const float4*)(wlin + k);
        float4 w1 = *(const float4*)(wlin + k + 4);
        acc += bflo(hv.x) * w0.x + bfhi(hv.x) * w0.y
             + bflo(hv.y) * w0.z + bfhi(hv.y) * w0.w
             + bflo(hv.z) * w1.x + bfhi(hv.z) * w1.y
             + bflo(hv.w) * w1.z + bfhi(hv.w) * w1.w;
    }
    #pragma unroll
    for (int s = 32; s >= 1; s >>= 1) acc += __shfl_xor(acc, s);
    if (l == 0) out[t] = 1.f / (1.f + expf(-(acc + blin[0])));
}

// ---------------------------------------------------------------------------
extern "C" void kernel_launch(void* const* d_in, const int* in_sizes, int n_in,
                              void* d_out, int out_size, void* d_ws, size_t ws_size,
                              hipStream_t stream)
{
    const float* input_seq = (const float*)d_in[0];
    const float* W_ih      = (const float*)d_in[1];
    const float* W_hh      = (const float*)d_in[2];
    const float* b_ih      = (const float*)d_in[3];
    const float* b_hh      = (const float*)d_in[4];
    const float* W_lin     = (const float*)d_in[5];
    const float* b_lin     = (const float*)d_in[6];
    float* out = (float*)d_out;
    char*  ws  = (char*)d_ws;

    unsigned long long* hbuf = (unsigned long long*)(ws + OFF_HBUF);
    uint32_t*           abf  = (uint32_t*)(ws + OFF_ABORT);
    __hip_bfloat16*     hs   = (__hip_bfloat16*)(ws + OFF_HS);
    __hip_bfloat16*     xpb  = (__hip_bfloat16*)(ws + OFF_XP);

    // zero hbuf tags + abort each call (harness does not re-poison between replays)
    hipMemsetAsync(ws, 0, 65536, stream);

    k_xproj<<<dim3(128 * 128), dim3(256), 0, stream>>>(input_seq, W_ih, b_ih, b_hh, xpb);

    constexpr int kLds = 32 * kWP * 2 + 2 * kH * 4;   // 148480 B
    hipFuncSetAttribute((const void*)k_lstm, hipFuncAttributeMaxDynamicSharedMemorySize, kLds);

    // Preferred: cooperative launch -> driver guarantees all 256 WGs co-resident,
    // so the tag-poll is provably live. Fallback: plain launch (whole-kernel
    // bounded spin + sticky abort still prevents any hang).
    {
        const float* a0 = W_hh; const __hip_bfloat16* a1 = xpb;
        unsigned long long* a2 = hbuf; uint32_t* a3 = abf; __hip_bfloat16* a4 = hs;
        void* args[5] = { &a0, &a1, &a2, &a3, &a4 };
        hipError_t ce = hipLaunchCooperativeKernel((const void*)k_lstm, dim3(kNB), dim3(256),
                                                   args, (unsigned)kLds, stream);
        if (ce != hipSuccess) {
            k_lstm<<<dim3(kNB), dim3(256), kLds, stream>>>(W_hh, xpb, hbuf, abf, hs);
        }
    }

    k_out<<<dim3(kSEQ / 4), dim3(256), 0, stream>>>(hs, W_lin, b_lin, out);
}

// Round 17
// 50469.437 us; speedup vs baseline: 1.8026x; 1.0535x over previous
//
#include <hip/hip_runtime.h>
#include <hip/hip_bf16.h>
#include <stdint.h>

constexpr int kSEQ = 8192;
constexpr int kIN  = 1024;
constexpr int kH   = 2048;
constexpr int kG4  = 4 * kH;   // 8192 gate rows
constexpr int kNB  = 256;      // persistent workgroups (1 per CU)
constexpr int kHB  = kH / kNB; // 8 h-values owned per WG
constexpr int kWP  = kH + 16;  // LDS weight row stride

// ---- workspace layout (bytes) ----
constexpr size_t OFF_HBUF  = 0;          // u64 hbuf[2][kH]  (32 KB) tagged h words
constexpr size_t OFF_ABORT = 32768;      // uint32 abort flag
constexpr size_t OFF_HS    = 65536;      // bf16 hs[kSEQ][kH]   (32 MB)
constexpr size_t OFF_XP    = OFF_HS + (size_t)kSEQ * kH * 2; // bf16 xp[kSEQ][kG4] (128 MB)

typedef unsigned int uint4v __attribute__((ext_vector_type(4)));
typedef __attribute__((ext_vector_type(8))) short bf16x8;
typedef __attribute__((ext_vector_type(4))) float f32x4;

__device__ __forceinline__ float bflo(uint32_t v) { return __uint_as_float(v << 16); }
__device__ __forceinline__ float bfhi(uint32_t v) { return __uint_as_float(v & 0xffff0000u); }

// ---------------------------------------------------------------------------
// Kernel 1 (R17: MFMA): x_proj[m][n] = input[m][:].W_ih[n][:] + b_ih[n]+b_hh[n]
// 128x128 C-tile, 4 waves as 2x2 of 64x64, mfma_f32_16x16x32_bf16, K-tile 32.
// LDS tiles padded to stride 40 bf16 (80B: 16B-aligned b128 frags, <=2-way banks).
// Fragment maps: A lane l -> A[l&15][(l>>4)*8+j]; B lane l -> B[(l>>4)*8+j][l&15];
// D lane l,reg r -> row (l>>4)*4+r, col l&15 (guide-verified C/D layout).
// ---------------------------------------------------------------------------
__global__ __launch_bounds__(256) void k_xproj(const float* __restrict__ A,
                                               const float* __restrict__ B,
                                               const float* __restrict__ bih,
                                               const float* __restrict__ bhh,
                                               __hip_bfloat16* __restrict__ C)
{
    constexpr int LDR = 40;   // bf16 units per LDS row (padded)
    __shared__ __hip_bfloat16 Al[128 * LDR];
    __shared__ __hip_bfloat16 Bl[128 * LDR];

    const int tid = threadIdx.x;
    const int bx  = blockIdx.x & 63;   // n tile
    const int by  = blockIdx.x >> 6;   // m tile
    const int m0  = by * 128, n0 = bx * 128;
    const int w   = tid >> 6;
    const int l   = tid & 63;
    const int wm  = w >> 1, wn = w & 1;    // 2x2 wave grid of 64x64
    const int fr  = l & 15, fg = l >> 4;   // fragment row / k-group

    f32x4 acc[4][4] = {};                  // [fm][fn]

    const int sr = tid >> 1;               // staging row 0..127
    const int sh = (tid & 1) << 4;         // k offset 0 / 16

    for (int k0 = 0; k0 < kIN; k0 += 32) {
        const float* as = A + (size_t)(m0 + sr) * kIN + k0 + sh;
        const float* bs = B + (size_t)(n0 + sr) * kIN + k0 + sh;
        float4 a0 = *(const float4*)(as);
        float4 a1 = *(const float4*)(as + 4);
        float4 a2 = *(const float4*)(as + 8);
        float4 a3 = *(const float4*)(as + 12);
        float4 b0 = *(const float4*)(bs);
        float4 b1 = *(const float4*)(bs + 4);
        float4 b2 = *(const float4*)(bs + 8);
        float4 b3 = *(const float4*)(bs + 12);
        __syncthreads();   // protect previous iteration's fragment reads
        {
            __hip_bfloat16* ad = Al + sr * LDR + sh;
            __hip_bfloat16* bd = Bl + sr * LDR + sh;
            ad[0]=__float2bfloat16(a0.x);  ad[1]=__float2bfloat16(a0.y);
            ad[2]=__float2bfloat16(a0.z);  ad[3]=__float2bfloat16(a0.w);
            ad[4]=__float2bfloat16(a1.x);  ad[5]=__float2bfloat16(a1.y);
            ad[6]=__float2bfloat16(a1.z);  ad[7]=__float2bfloat16(a1.w);
            ad[8]=__float2bfloat16(a2.x);  ad[9]=__float2bfloat16(a2.y);
            ad[10]=__float2bfloat16(a2.z); ad[11]=__float2bfloat16(a2.w);
            ad[12]=__float2bfloat16(a3.x); ad[13]=__float2bfloat16(a3.y);
            ad[14]=__float2bfloat16(a3.z); ad[15]=__float2bfloat16(a3.w);
            bd[0]=__float2bfloat16(b0.x);  bd[1]=__float2bfloat16(b0.y);
            bd[2]=__float2bfloat16(b0.z);  bd[3]=__float2bfloat16(b0.w);
            bd[4]=__float2bfloat16(b1.x);  bd[5]=__float2bfloat16(b1.y);
            bd[6]=__float2bfloat16(b1.z);  bd[7]=__float2bfloat16(b1.w);
            bd[8]=__float2bfloat16(b2.x);  bd[9]=__float2bfloat16(b2.y);
            bd[10]=__float2bfloat16(b2.z); bd[11]=__float2bfloat16(b2.w);
            bd[12]=__float2bfloat16(b3.x); bd[13]=__float2bfloat16(b3.y);
            bd[14]=__float2bfloat16(b3.z); bd[15]=__float2bfloat16(b3.w);
        }
        __syncthreads();

        bf16x8 am[4], bn[4];
        #pragma unroll
        for (int f = 0; f < 4; ++f) {
            am[f] = *(const bf16x8*)(Al + (wm * 64 + f * 16 + fr) * LDR + fg * 8);
            bn[f] = *(const bf16x8*)(Bl + (wn * 64 + f * 16 + fr) * LDR + fg * 8);
        }
        #pragma unroll
        for (int fm = 0; fm < 4; ++fm)
            #pragma unroll
            for (int fn = 0; fn < 4; ++fn)
                acc[fm][fn] = __builtin_amdgcn_mfma_f32_16x16x32_bf16(
                                  am[fm], bn[fn], acc[fm][fn], 0, 0, 0);
    }

    // epilogue: D row=(l>>4)*4+r, col=l&15 ; add bias, store bf16
    #pragma unroll
    for (int fn = 0; fn < 4; ++fn) {
        const int cn = n0 + wn * 64 + fn * 16 + fr;
        const float bb = bih[cn] + bhh[cn];
        #pragma unroll
        for (int fm = 0; fm < 4; ++fm) {
            const int rbase = m0 + wm * 64 + fm * 16 + fg * 4;
            #pragma unroll
            for (int r = 0; r < 4; ++r)
                C[(size_t)(rbase + r) * kG4 + cn] = __float2bfloat16(acc[fm][fn][r] + bb);
        }
    }
}

// ---------------------------------------------------------------------------
// Kernel 2: persistent LSTM recurrence. BYTE-IDENTICAL to R16 (best: 50.4 ms).
// 1-hop data-carrying tagged sync, 4x global_load_dwordx4 sc0 sc1 poll sweep,
// single barrier/step, per-wave gate collection, bounded budget + sticky abort.
// ---------------------------------------------------------------------------
__global__ __launch_bounds__(256, 1) void k_lstm(const float* __restrict__ Whh,
                                                 const __hip_bfloat16* __restrict__ xp,
                                                 unsigned long long* __restrict__ hbuf, // [2][kH]
                                                 uint32_t* __restrict__ abortf,
                                                 __hip_bfloat16* __restrict__ hs)
{
    extern __shared__ char smem[];
    __hip_bfloat16* Wl  = (__hip_bfloat16*)smem;              // [32][kWP] bf16
    float*          hl2 = (float*)(smem + 32 * kWP * 2);      // [2][kH] fp32

    const int wg  = blockIdx.x;
    const int tid = threadIdx.x;
    const int w   = tid >> 6;   // wave id
    const int l   = tid & 63;
    const int hb  = wg * kHB;

    // ---- one-time: stage W_hh slice, per-wave gate-complete mapping ----
    {
        const int lr = tid >> 3;
        const int g  = lr & 3;
        const int jl = 2 * (lr >> 3) + ((lr >> 2) & 1);
        const int cb = (tid & 7) * 256;
        const float* src = Whh + (size_t)(g * kH + hb + jl) * kH + cb;
        __hip_bfloat16* dst = Wl + (size_t)lr * kWP + cb;
        for (int c = 0; c < 256; c += 4) {
            float4 v = *(const float4*)(src + c);
            dst[c + 0] = __float2bfloat16(v.x);
            dst[c + 1] = __float2bfloat16(v.y);
            dst[c + 2] = __float2bfloat16(v.z);
            dst[c + 3] = __float2bfloat16(v.w);
        }
    }
    __syncthreads();

    const __hip_bfloat16* wrow = Wl + (size_t)(w * 8 + (l >> 3)) * kWP;
    const int kbase = (l & 7) * 8;
    const int jg = hb + 2 * w + (l >> 5);     // this half-wave's h index (global)
    float c_state = 0.0f;
    uint32_t budget = 0;                      // whole-kernel retry budget

    for (int t = 0; t < kSEQ; ++t) {
        // ---- issue this lane's 4 x_proj gate values early (retire under poll) ----
        const __hip_bfloat16* xr = xp + (size_t)t * kG4 + jg;
        const float xi = __bfloat162float(xr[0]);
        const float xf = __bfloat162float(xr[kH]);
        const float xg = __bfloat162float(xr[2 * kH]);
        const float xo = __bfloat162float(xr[3 * kH]);

        // ---- gather h_{t-1} into hl2[t&1]: 64B/thread coherent sweep ----
        float* hw = hl2 + (size_t)(t & 1) * kH + tid * 8;
        int dead = 0;
        if (t == 0) {
            #pragma unroll
            for (int j = 0; j < 8; ++j) hw[j] = 0.f;
        } else {
            const unsigned long long* src = hbuf + (size_t)((t - 1) & 1) * kH + tid * 8;
            const uint32_t tag = (uint32_t)t;
            uint4v q0, q1, q2, q3;
            for (;;) {
                asm volatile(
                    "global_load_dwordx4 %0, %4, off sc0 sc1\n\t"
                    "global_load_dwordx4 %1, %4, off offset:16 sc0 sc1\n\t"
                    "global_load_dwordx4 %2, %4, off offset:32 sc0 sc1\n\t"
                    "global_load_dwordx4 %3, %4, off offset:48 sc0 sc1\n\t"
                    "s_waitcnt vmcnt(0)"
                    : "=&v"(q0), "=&v"(q1), "=&v"(q2), "=&v"(q3)
                    : "v"(src)
                    : "memory");
                bool ok = (q0[0] == tag) & (q0[2] == tag) & (q1[0] == tag) & (q1[2] == tag)
                        & (q2[0] == tag) & (q2[2] == tag) & (q3[0] == tag) & (q3[2] == tag);
                if (ok) break;
                if ((++budget & 15) == 0) {
                    if (__hip_atomic_load(abortf, __ATOMIC_RELAXED,
                                          __HIP_MEMORY_SCOPE_AGENT) != 0u) { dead = 1; break; }
                    if (budget > (1u << 21)) { dead = 1; break; }
                }
            }
            hw[0] = __uint_as_float(q0[1]); hw[1] = __uint_as_float(q0[3]);
            hw[2] = __uint_as_float(q1[1]); hw[3] = __uint_as_float(q1[3]);
            hw[4] = __uint_as_float(q2[1]); hw[5] = __uint_as_float(q2[3]);
            hw[6] = __uint_as_float(q3[1]); hw[7] = __uint_as_float(q3[3]);
        }
        if (__syncthreads_or(dead)) {   // single barrier/step; uniform exit
            __hip_atomic_store(abortf, 1u, __ATOMIC_RELAXED, __HIP_MEMORY_SCOPE_AGENT);
            return;
        }

        // ---- matvec: lane group r=l>>3 -> LDS row w*8+r; 32 iters x 8 MACs ----
        const float* hv = hl2 + (size_t)(t & 1) * kH;
        float acc = 0.f;
        #pragma unroll 8
        for (int it = 0; it < 32; ++it) {
            const int k = it * 64 + kbase;
            uint4 wv = *(const uint4*)(wrow + k);
            float4 h0 = *(const float4*)(hv + k);
            float4 h1 = *(const float4*)(hv + k + 4);
            acc += bflo(wv.x) * h0.x + bfhi(wv.x) * h0.y
                 + bflo(wv.y) * h0.z + bfhi(wv.y) * h0.w
                 + bflo(wv.z) * h1.x + bfhi(wv.z) * h1.y
                 + bflo(wv.w) * h1.z + bfhi(wv.w) * h1.w;
        }
        acc += __shfl_xor(acc, 1);
        acc += __shfl_xor(acc, 2);
        acc += __shfl_xor(acc, 4);   // every lane of each 8-group has its row sum

        // ---- collect 4 gates for this half-wave's h index; update; publish ----
        const int base = l & 32;
        const float gi = __shfl(acc, base + 0)  + xi;
        const float gf = __shfl(acc, base + 8)  + xf;
        const float gg = __shfl(acc, base + 16) + xg;
        const float go = __shfl(acc, base + 24) + xo;
        const float si = 1.f / (1.f + expf(-gi));
        const float sf = 1.f / (1.f + expf(-gf));
        const float tg = tanhf(gg);
        const float so = 1.f / (1.f + expf(-go));
        c_state = sf * c_state + si * tg;            // valid per half-wave
        const float hvv = so * tanhf(c_state);
        if ((l & 31) == 0) {
            hs[(size_t)t * kH + jg] = __float2bfloat16(hvv);
            const unsigned long long pv =
                ((unsigned long long)__float_as_uint(hvv) << 32) | (uint32_t)(t + 1);
            __hip_atomic_store(hbuf + (size_t)(t & 1) * kH + jg, pv,
                               __ATOMIC_RELAXED, __HIP_MEMORY_SCOPE_AGENT);
        }
        // no trailing barrier: tags + next step's single barrier self-synchronize
    }
}

// ---------------------------------------------------------------------------
// Kernel 3: out[t] = sigmoid(hs[t] . W_lin + b_lin). One wave per t.
// ---------------------------------------------------------------------------
__global__ __launch_bounds__(256) void k_out(const __hip_bfloat16* __restrict__ hs,
                                             const float* __restrict__ wlin,
                                             const float* __restrict__ blin,
                                             float* __restrict__ out)
{
    const int w = threadIdx.x >> 6, l = threadIdx.x & 63;
    const int t = blockIdx.x * 4 + w;
    const __hip_bfloat16* row = hs + (size_t)t * kH;
    float acc = 0.f;
    #pragma unroll
    for (int i = 0; i < 4; ++i) {
        const int k = i * 512 + l * 8;
        uint4 hv = *(const uint4*)(row + k);
        float4 w0 = *(const float4*)(wlin + k);
        float4 w1 = *(const float4*)(wlin + k + 4);
        acc += bflo(hv.x) * w0.x + bfhi(hv.x) * w0.y
             + bflo(hv.y) * w0.z + bfhi(hv.y) * w0.w
             + bflo(hv.z) * w1.x + bfhi(hv.z) * w1.y
             + bflo(hv.w) * w1.z + bfhi(hv.w) * w1.w;
    }
    #pragma unroll
    for (int s = 32; s >= 1; s >>= 1) acc += __shfl_xor(acc, s);
    if (l == 0) out[t] = 1.f / (1.f + expf(-(acc + blin[0])));
}

// ---------------------------------------------------------------------------
extern "C" void kernel_launch(void* const* d_in, const int* in_sizes, int n_in,
                              void* d_out, int out_size, void* d_ws, size_t ws_size,
                              hipStream_t stream)
{
    const float* input_seq = (const float*)d_in[0];
    const float* W_ih      = (const float*)d_in[1];
    const float* W_hh      = (const float*)d_in[2];
    const float* b_ih      = (const float*)d_in[3];
    const float* b_hh      = (const float*)d_in[4];
    const float* W_lin     = (const float*)d_in[5];
    const float* b_lin     = (const float*)d_in[6];
    float* out = (float*)d_out;
    char*  ws  = (char*)d_ws;

    unsigned long long* hbuf = (unsigned long long*)(ws + OFF_HBUF);
    uint32_t*           abf  = (uint32_t*)(ws + OFF_ABORT);
    __hip_bfloat16*     hs   = (__hip_bfloat16*)(ws + OFF_HS);
    __hip_bfloat16*     xpb  = (__hip_bfloat16*)(ws + OFF_XP);

    // zero hbuf tags + abort each call (harness does not re-poison between replays)
    hipMemsetAsync(ws, 0, 65536, stream);

    k_xproj<<<dim3(64 * 64), dim3(256), 0, stream>>>(input_seq, W_ih, b_ih, b_hh, xpb);

    constexpr int kLds = 32 * kWP * 2 + 2 * kH * 4;   // 148480 B
    hipFuncSetAttribute((const void*)k_lstm, hipFuncAttributeMaxDynamicSharedMemorySize, kLds);

    // Preferred: cooperative launch -> driver guarantees all 256 WGs co-resident,
    // so the tag-poll is provably live. Fallback: plain launch (whole-kernel
    // bounded spin + sticky abort still prevents any hang).
    {
        const float* a0 = W_hh; const __hip_bfloat16* a1 = xpb;
        unsigned long long* a2 = hbuf; uint32_t* a3 = abf; __hip_bfloat16* a4 = hs;
        void* args[5] = { &a0, &a1, &a2, &a3, &a4 };
        hipError_t ce = hipLaunchCooperativeKernel((const void*)k_lstm, dim3(kNB), dim3(256),
                                                   args, (unsigned)kLds, stream);
        if (ce != hipSuccess) {
            k_lstm<<<dim3(kNB), dim3(256), kLds, stream>>>(W_hh, xpb, hbuf, abf, hs);
        }
    }

    k_out<<<dim3(kSEQ / 4), dim3(256), 0, stream>>>(hs, W_lin, b_lin, out);
}